// Round 1
// baseline (8360.953 us; speedup 1.0000x reference)
//
#include <hip/hip_runtime.h>
#include <stdint.h>

// ScannedRNN: T=1024, B=128, D=512 GRU with resets + straight-through clip.
// Plan: prep (weight convert/pack) -> gemmA (gi = x@Wi+bi, bf16) -> rnnB
// (persistent 128-block recurrent kernel, LDS-resident Wh, per-rowgroup
// counter barrier through agent-scope atomics).

typedef float f32x4 __attribute__((ext_vector_type(4)));
typedef short s16x8 __attribute__((ext_vector_type(8)));

#define DD 512
#define BB 128
#define TT 1024

static __device__ __forceinline__ unsigned short f2bf(float f) {
  uint32_t u = __builtin_bit_cast(uint32_t, f);
  u = (u + 0x7fffu + ((u >> 16) & 1u)) >> 16;   // RNE
  return (unsigned short)u;
}
static __device__ __forceinline__ float b2f(uint32_t bits) {
  return __builtin_bit_cast(float, bits << 16);
}
static __device__ __forceinline__ s16x8 ldsfrag(const char* p) {
  return __builtin_bit_cast(s16x8, *reinterpret_cast<const uint4*>(p));
}

// ---------------- prep: convert weights to bf16, packed layouts ----------------
// WiT[n][k]  (n=0..1535, k=0..511)  : transposed Wi for gemmA B-operand
// Wpack[cj][c96][k] (cj=0..15, c96=0..95, k=0..511): per-column-block Wh slice,
//   c96 = gate*32 + cc, gate 0=r (Wh_rz col cc+cj*32), 1=z (Wh_rz col 512+...), 2=n (Whn)
__global__ void prep(const float* __restrict__ Wi, const float* __restrict__ Whrz,
                     const float* __restrict__ Whn,
                     unsigned short* __restrict__ WiT, unsigned short* __restrict__ Wpk) {
  int i = blockIdx.x * 256 + threadIdx.x;
  if (i < 786432) {
    int n = i >> 9, k = i & 511;
    WiT[i] = f2bf(Wi[(size_t)k * 1536 + n]);
  } else {
    int j = i - 786432;
    int ck = j >> 9;
    int k = j & 511;
    int cj = ck / 96, c96 = ck % 96;
    int g = c96 >> 5, cc = c96 & 31;
    float v = (g < 2) ? Whrz[(size_t)k * 1024 + g * 512 + cj * 32 + cc]
                      : Whn[(size_t)k * 512 + cj * 32 + cc];
    Wpk[j] = f2bf(v);
  }
}

// ---------------- resets dtype probe (bool bytes vs int32) ----------------
__global__ void scanR(const int* __restrict__ r, int* __restrict__ flag) {
  int i = blockIdx.x * 256 + threadIdx.x;       // 32768 ints = 131072 bytes, safe
  unsigned int v = (unsigned int)r[i];
  if (v > 1u) atomicOr(flag, 1);
}

// ---------------- gemmA: gi[M][1536] = x[M][512] @ Wi + bi (bf16 out) ----------------
// 128x128 tile, 256 threads, 4 waves of 64x64. A reg-staged f32->bf16, B bf16.
__global__ __launch_bounds__(256) void gemmA(const float* __restrict__ x,
                                             const unsigned short* __restrict__ WiT,
                                             const float* __restrict__ bi,
                                             unsigned short* __restrict__ gi) {
  __shared__ unsigned short Al[128 * 64];  // [m][k] xor-swizzled
  __shared__ unsigned short Bl[128 * 64];  // [n][k] xor-swizzled
  const int tid = threadIdx.x;
  const int lane = tid & 63;
  const int wv = tid >> 6;
  const int wm = wv >> 1, wn = wv & 1;
  const int n0 = blockIdx.x * 128;   // N fastest: 12 consecutive blocks share A panel (L2/L3 reuse)
  const int m0 = blockIdx.y * 128;

  const int sr = tid >> 1;     // staging row (A row m / B row n)
  const int sh = tid & 1;      // k-half (32 elems)
  const float* xp = x + (size_t)(m0 + sr) * DD + sh * 32;
  const unsigned short* wp = WiT + (size_t)(n0 + sr) * DD + sh * 32;

  float bir[4];
#pragma unroll
  for (int j = 0; j < 4; ++j) bir[j] = bi[n0 + wn * 64 + j * 16 + (lane & 15)];

  f32x4 acc[4][4];
#pragma unroll
  for (int i = 0; i < 4; ++i)
#pragma unroll
    for (int j = 0; j < 4; ++j) acc[i][j] = (f32x4){0.f, 0.f, 0.f, 0.f};

  float4 xa[8];
  uint4 wa[4];
#pragma unroll
  for (int q = 0; q < 8; ++q) xa[q] = *reinterpret_cast<const float4*>(xp + q * 4);
#pragma unroll
  for (int c = 0; c < 4; ++c) wa[c] = *reinterpret_cast<const uint4*>(wp + c * 8);

  for (int kt = 0; kt < 8; ++kt) {
    __syncthreads();
    const int swz = (sr & 7) << 4;
#pragma unroll
    for (int c = 0; c < 4; ++c) {
      const float4 a = xa[2 * c], b = xa[2 * c + 1];
      uint4 u;
      u.x = (uint32_t)f2bf(a.x) | ((uint32_t)f2bf(a.y) << 16);
      u.y = (uint32_t)f2bf(a.z) | ((uint32_t)f2bf(a.w) << 16);
      u.z = (uint32_t)f2bf(b.x) | ((uint32_t)f2bf(b.y) << 16);
      u.w = (uint32_t)f2bf(b.z) | ((uint32_t)f2bf(b.w) << 16);
      const int off = sr * 128 + ((sh * 64 + c * 16) ^ swz);
      *reinterpret_cast<uint4*>(reinterpret_cast<char*>(Al) + off) = u;
    }
#pragma unroll
    for (int c = 0; c < 4; ++c) {
      const int off = sr * 128 + ((sh * 64 + c * 16) ^ swz);
      *reinterpret_cast<uint4*>(reinterpret_cast<char*>(Bl) + off) = wa[c];
    }
    if (kt < 7) {
#pragma unroll
      for (int q = 0; q < 8; ++q)
        xa[q] = *reinterpret_cast<const float4*>(xp + (kt + 1) * 64 + q * 4);
#pragma unroll
      for (int c = 0; c < 4; ++c)
        wa[c] = *reinterpret_cast<const uint4*>(wp + (kt + 1) * 64 + c * 8);
    }
    __syncthreads();
#pragma unroll
    for (int kk = 0; kk < 2; ++kk) {
      s16x8 af[4], bfr[4];
      const int kb = kk * 64 + ((lane >> 4) << 4);
      const int sw = (lane & 7) << 4;
#pragma unroll
      for (int i = 0; i < 4; ++i) {
        const int row = wm * 64 + i * 16 + (lane & 15);
        af[i] = ldsfrag(reinterpret_cast<const char*>(Al) + row * 128 + (kb ^ sw));
      }
#pragma unroll
      for (int j = 0; j < 4; ++j) {
        const int row = wn * 64 + j * 16 + (lane & 15);
        bfr[j] = ldsfrag(reinterpret_cast<const char*>(Bl) + row * 128 + (kb ^ sw));
      }
#pragma unroll
      for (int i = 0; i < 4; ++i)
#pragma unroll
        for (int j = 0; j < 4; ++j)
          acc[i][j] = __builtin_amdgcn_mfma_f32_16x16x32_bf16(af[i], bfr[j], acc[i][j], 0, 0, 0);
    }
  }
#pragma unroll
  for (int i = 0; i < 4; ++i) {
    const int gr0 = m0 + wm * 64 + i * 16 + ((lane >> 4) << 2);
#pragma unroll
    for (int j = 0; j < 4; ++j) {
      const int gc = n0 + wn * 64 + j * 16 + (lane & 15);
#pragma unroll
      for (int r = 0; r < 4; ++r)
        gi[(size_t)(gr0 + r) * 1536 + gc] = f2bf(acc[i][j][r] + bir[j]);
    }
  }
}

// ---------------- rnnB: persistent recurrent kernel ----------------
// 128 blocks = 16 column-blocks (cj = bid>>3) x 8 row groups (rg = bid&7).
// Block owns cols [cj*32, cj*32+32) of r,z,n and rows [rg*16, rg*16+16).
// Wh slice (512 x 96 bf16, col-major, xor-swizzled) resident in LDS.
// Per step: MFMA (8 waves: 2 col-halves x 4 K-splits) -> LDS reduce ->
// elementwise GRU update (1 elem/thread, f32 carry in register) ->
// agent-scope h exchange + per-rowgroup counter barrier -> restage h.
#define RNN_SMEM (98304 + 16384 + 26112)

__global__ __launch_bounds__(512) void rnnB(const unsigned short* __restrict__ gi,
                                            const unsigned short* __restrict__ Wpk,
                                            const float* __restrict__ bhn,
                                            const int* __restrict__ resets,
                                            float* __restrict__ hbuf,      // [2][128][512] f32
                                            unsigned int* __restrict__ cnt,// [8][1024]
                                            const int* __restrict__ rmodep,
                                            float* __restrict__ ys,
                                            int t0, int tc) {
  extern __shared__ char smem[];
  unsigned short* Wl = reinterpret_cast<unsigned short*>(smem);            // [96][512] swz
  unsigned short* Hl = reinterpret_cast<unsigned short*>(smem + 98304);    // [16][512] swz
  float* ax = reinterpret_cast<float*>(smem + 98304 + 16384);              // [4][2][3][16*17]

  const int tid = threadIdx.x;
  const int lane = tid & 63;
  const int wv = tid >> 6;
  const int w = wv & 1, ks = wv >> 1;
  const int cj = blockIdx.x >> 3, rg = blockIdx.x & 7;
  const int ec = tid & 31, eb = tid >> 5;          // elementwise: col-in-32, row-in-16
  const int bglob = rg * 16 + eb;
  const int colglob = cj * 32 + ec;
  const int rmode = *rmodep;
  const unsigned char* rbytes = reinterpret_cast<const unsigned char*>(resets);

  // stage Wh slice: linear LDS dest, inverse-swizzled source chunk
  {
    const unsigned short* wsrc = Wpk + (size_t)cj * 96 * 512;
    for (int q = 0; q < 12; ++q) {
      const int chunk = q * 512 + tid;
      const int col = chunk >> 6;
      const int co = chunk & 63;
      uint4 v = *reinterpret_cast<const uint4*>(wsrc + col * 512 + ((co ^ (col & 7)) << 3));
      *reinterpret_cast<uint4*>(smem + col * 1024 + co * 16) = v;
    }
  }
  const float bhn_c = bhn[colglob];
  float h_old = hbuf[(size_t)bglob * 512 + colglob];   // parity 0, f32 carry

  int rst = rmode ? (int)rbytes[t0 * 128 + bglob] : resets[t0 * 128 + bglob];
  uint32_t gir, giz, gin;
  {
    const unsigned short* gp = gi + (size_t)bglob * 1536 + colglob;  // t=0
    gir = gp[0]; giz = gp[512]; gin = gp[1024];
  }
  // stage h(0): rows rg*16+eb, cols ec*16..+15, reset-masked, bf16, swizzled
  {
    const float* src = hbuf + (size_t)bglob * 512 + ec * 16;
    float v[16];
#pragma unroll
    for (int i = 0; i < 16; ++i) v[i] = src[i];
    if (rst) {
#pragma unroll
      for (int i = 0; i < 16; ++i) v[i] = 0.f;
    }
    const int swz = (eb & 7) << 4;
#pragma unroll
    for (int j = 0; j < 2; ++j) {
      uint4 u;
      u.x = (uint32_t)f2bf(v[8 * j + 0]) | ((uint32_t)f2bf(v[8 * j + 1]) << 16);
      u.y = (uint32_t)f2bf(v[8 * j + 2]) | ((uint32_t)f2bf(v[8 * j + 3]) << 16);
      u.z = (uint32_t)f2bf(v[8 * j + 4]) | ((uint32_t)f2bf(v[8 * j + 5]) << 16);
      u.w = (uint32_t)f2bf(v[8 * j + 6]) | ((uint32_t)f2bf(v[8 * j + 7]) << 16);
      const int off = eb * 1024 + ((ec * 32 + j * 16) ^ swz);
      *reinterpret_cast<uint4*>(reinterpret_cast<char*>(Hl) + off) = u;
    }
  }
  __syncthreads();

  for (int t = 0; t < tc; ++t) {
    const int tg = t0 + t;
    const bool haveN = (t + 1 < tc);
    uint32_t ngr = 0, ngz = 0, ngn = 0;
    int nrst = 0;
    if (haveN) {  // prefetch next step's gi + reset (independent of barrier)
      const unsigned short* gp = gi + ((size_t)(t + 1) * 128 + bglob) * 1536 + colglob;
      ngr = gp[0]; ngz = gp[512]; ngn = gp[1024];
      nrst = rmode ? (int)rbytes[(tg + 1) * 128 + bglob] : resets[(tg + 1) * 128 + bglob];
    }
    // ---- MFMA: out[col][row] partials over K-quarter ks, col-half w ----
    f32x4 acc[3];
#pragma unroll
    for (int g = 0; g < 3; ++g) acc[g] = (f32x4){0.f, 0.f, 0.f, 0.f};
    {
      const int rowb = lane & 15;
      const int kplus = (lane >> 4) << 4;
      const char* hrow = reinterpret_cast<const char*>(Hl) + rowb * 1024;
      const int hsw = (rowb & 7) << 4;
#pragma unroll
      for (int g = 0; g < 3; ++g) {
        const int col = g * 32 + w * 16 + (lane & 15);
        const char* wrow = reinterpret_cast<const char*>(Wl) + col * 1024;
        const int wsw = (col & 7) << 4;
#pragma unroll
        for (int kk = 0; kk < 4; ++kk) {
          const int kb = (ks * 128 + kk * 32) * 2 + kplus;
          s16x8 a = ldsfrag(wrow + (kb ^ wsw));
          s16x8 b = ldsfrag(hrow + (kb ^ hsw));
          acc[g] = __builtin_amdgcn_mfma_f32_16x16x32_bf16(a, b, acc[g], 0, 0, 0);
        }
      }
    }
    {  // partials -> LDS (padded stride 17 to avoid bank conflicts)
      const int mh = (lane >> 4) << 2, nn = lane & 15;
#pragma unroll
      for (int g = 0; g < 3; ++g) {
        float* dst = ax + ((ks * 2 + w) * 3 + g) * 272 + nn;
#pragma unroll
        for (int r = 0; r < 4; ++r) dst[(mh + r) * 17] = acc[g][r];
      }
    }
    __syncthreads();  // S1
    // ---- elementwise GRU update: one (row eb, col ec) per thread ----
    {
      const int wc = ec >> 4, mc = ec & 15;
      float s0 = 0.f, s1 = 0.f, s2 = 0.f;
#pragma unroll
      for (int k2 = 0; k2 < 4; ++k2) {
        const float* p = ax + ((k2 * 2 + wc) * 3) * 272 + mc * 17 + eb;
        s0 += p[0]; s1 += p[272]; s2 += p[544];
      }
      const float r = 1.f / (1.f + __expf(-(b2f(gir) + s0)));
      const float z = 1.f / (1.f + __expf(-(b2f(giz) + s1)));
      const float hu = rst ? 0.f : h_old;
      const float pre = b2f(gin) + r * (s2 + bhn_c);
      const float n = 1.f - 2.f / (1.f + __expf(2.f * pre));
      float hn = (1.f - z) * n + z * hu;
      hn = fminf(1.f, fmaxf(-1.f, hn));
      __builtin_nontemporal_store(hn, ys + ((size_t)tg * 128 + bglob) * 512 + colglob);
      float* hb = hbuf + (size_t)((t & 1) ^ 1) * 65536 + (size_t)bglob * 512 + colglob;
      __hip_atomic_store(hb, hn, __ATOMIC_RELAXED, __HIP_MEMORY_SCOPE_AGENT);
      h_old = hn;
    }
    if (haveN) {
      __syncthreads();  // S2: drains each wave's vmcnt -> sc1 stores at coherence point
      unsigned int* cp = cnt + rg * 1024 + tg;
      if (tid == 0)
        __hip_atomic_fetch_add(cp, 1u, __ATOMIC_RELAXED, __HIP_MEMORY_SCOPE_AGENT);
      if (lane == 0) {
        while (__hip_atomic_load(cp, __ATOMIC_RELAXED, __HIP_MEMORY_SCOPE_AGENT) < 16u)
          __builtin_amdgcn_s_sleep(1);
      }
      __syncthreads();  // S3
      // ---- restage h(t+1) (coherent loads bypass stale L1/L2) ----
      const float* src = hbuf + (size_t)((t & 1) ^ 1) * 65536 + (size_t)bglob * 512 + ec * 16;
      float v[16];
#pragma unroll
      for (int i = 0; i < 16; ++i)
        v[i] = __hip_atomic_load(src + i, __ATOMIC_RELAXED, __HIP_MEMORY_SCOPE_AGENT);
      if (nrst) {
#pragma unroll
        for (int i = 0; i < 16; ++i) v[i] = 0.f;
      }
      const int swz = (eb & 7) << 4;
#pragma unroll
      for (int j = 0; j < 2; ++j) {
        uint4 u;
        u.x = (uint32_t)f2bf(v[8 * j + 0]) | ((uint32_t)f2bf(v[8 * j + 1]) << 16);
        u.y = (uint32_t)f2bf(v[8 * j + 2]) | ((uint32_t)f2bf(v[8 * j + 3]) << 16);
        u.z = (uint32_t)f2bf(v[8 * j + 4]) | ((uint32_t)f2bf(v[8 * j + 5]) << 16);
        u.w = (uint32_t)f2bf(v[8 * j + 6]) | ((uint32_t)f2bf(v[8 * j + 7]) << 16);
        const int off = eb * 1024 + ((ec * 32 + j * 16) ^ swz);
        *reinterpret_cast<uint4*>(reinterpret_cast<char*>(Hl) + off) = u;
      }
      __syncthreads();  // S4
      gir = ngr; giz = ngz; gin = ngn; rst = nrst;
    }
  }
}

// ---------------- launch ----------------
extern "C" void kernel_launch(void* const* d_in, const int* in_sizes, int n_in,
                              void* d_out, int out_size, void* d_ws, size_t ws_size,
                              hipStream_t stream) {
  const float* h0 = (const float*)d_in[0];
  const float* ins = (const float*)d_in[1];
  const int* rst = (const int*)d_in[2];
  const float* Wi = (const float*)d_in[3];
  const float* bi = (const float*)d_in[4];
  const float* Whrz = (const float*)d_in[5];
  const float* Whn = (const float*)d_in[6];
  const float* bhn = (const float*)d_in[7];
  float* ys = (float*)d_out;

  char* ws = (char*)d_ws;
  unsigned short* WiT = (unsigned short*)(ws);              // 1,572,864 B
  unsigned short* Wpk = (unsigned short*)(ws + 1572864);    // 1,572,864 B
  float* hbuf = (float*)(ws + 3145728);                     //   524,288 B
  unsigned int* cnt = (unsigned int*)(ws + 3670016);        //    32,768 B
  int* flag = (int*)(ws + 3702784);                         // 4 B (+pad to 4096)
  const size_t gi_off = 3706880;
  unsigned short* gi = (unsigned short*)(ws + gi_off);

  size_t avail = (ws_size > gi_off) ? (ws_size - gi_off) : 0;
  long long tcap = (long long)(avail / (128ull * 1536ull * 2ull));
  int Tc = (int)((tcap > 1024) ? 1024 : tcap);
  Tc &= ~1;
  if (Tc < 2) Tc = 2;

  hipMemsetAsync(cnt, 0, 36864, stream);  // counters + rmode flag
  hipMemcpyAsync(hbuf, h0, 262144, hipMemcpyDeviceToDevice, stream);  // h carry parity 0
  prep<<<dim3(6144), dim3(256), 0, stream>>>(Wi, Whrz, Whn, WiT, Wpk);
  scanR<<<dim3(128), dim3(256), 0, stream>>>(rst, flag);
  hipFuncSetAttribute((const void*)rnnB, hipFuncAttributeMaxDynamicSharedMemorySize, RNN_SMEM);

  for (int t0 = 0; t0 < 1024; t0 += Tc) {
    int tc = 1024 - t0;
    if (tc > Tc) tc = Tc;
    gemmA<<<dim3(12, tc), dim3(256), 0, stream>>>(ins + (size_t)t0 * 65536, WiT, bi, gi);
    rnnB<<<dim3(128), dim3(512), RNN_SMEM, stream>>>(gi, Wpk, bhn, rst, hbuf, cnt, flag, ys,
                                                     t0, tc);
  }
}

// Round 3
// 4183.694 us; speedup vs baseline: 1.9985x; 1.9985x over previous
//
#include <hip/hip_runtime.h>
#include <stdint.h>

// ScannedRNN: T=1024, B=128, D=512 GRU with resets + straight-through clip.
// prep (weight convert/pack) -> gemmA (gi = x@Wi+bi, bf16) -> rnnB
// (persistent 128-block recurrent kernel, LDS-resident Wh; per-rowgroup
// epoch-flag barrier; ALL cross-block traffic agent-scope (proven r1
// semantics); coalesced column-owner h exchange; bounded-poll watchdog).

typedef float f32x4 __attribute__((ext_vector_type(4)));
typedef short s16x8 __attribute__((ext_vector_type(8)));

#define DD 512
#define BB 128
#define TT 1024

static __device__ __forceinline__ unsigned short f2bf(float f) {
  uint32_t u = __builtin_bit_cast(uint32_t, f);
  u = (u + 0x7fffu + ((u >> 16) & 1u)) >> 16;   // RNE
  return (unsigned short)u;
}
static __device__ __forceinline__ float b2f(uint32_t bits) {
  return __builtin_bit_cast(float, bits << 16);
}
static __device__ __forceinline__ s16x8 ldsfrag(const char* p) {
  return __builtin_bit_cast(s16x8, *reinterpret_cast<const uint4*>(p));
}

// ---------------- prep: convert weights to bf16, packed layouts ----------------
__global__ void prep(const float* __restrict__ Wi, const float* __restrict__ Whrz,
                     const float* __restrict__ Whn,
                     unsigned short* __restrict__ WiT, unsigned short* __restrict__ Wpk) {
  int i = blockIdx.x * 256 + threadIdx.x;
  if (i < 786432) {
    int n = i >> 9, k = i & 511;
    WiT[i] = f2bf(Wi[(size_t)k * 1536 + n]);
  } else {
    int j = i - 786432;
    int ck = j >> 9;
    int k = j & 511;
    int cj = ck / 96, c96 = ck % 96;
    int g = c96 >> 5, cc = c96 & 31;
    float v = (g < 2) ? Whrz[(size_t)k * 1024 + g * 512 + cj * 32 + cc]
                      : Whn[(size_t)k * 512 + cj * 32 + cc];
    Wpk[j] = f2bf(v);
  }
}

// ---------------- resets dtype probe (bool bytes vs int32) ----------------
__global__ void scanR(const int* __restrict__ r, int* __restrict__ flag) {
  int i = blockIdx.x * 256 + threadIdx.x;       // 32768 ints = 131072 bytes, safe
  unsigned int v = (unsigned int)r[i];
  if (v > 1u) atomicOr(flag, 1);
}

// ---------------- gemmA: gi[M][1536] = x[M][512] @ Wi + bi (bf16 out) ----------------
__global__ __launch_bounds__(256) void gemmA(const float* __restrict__ x,
                                             const unsigned short* __restrict__ WiT,
                                             const float* __restrict__ bi,
                                             unsigned short* __restrict__ gi) {
  __shared__ unsigned short Al[128 * 64];
  __shared__ unsigned short Bl[128 * 64];
  const int tid = threadIdx.x;
  const int lane = tid & 63;
  const int wv = tid >> 6;
  const int wm = wv >> 1, wn = wv & 1;
  const int n0 = blockIdx.x * 128;
  const int m0 = blockIdx.y * 128;

  const int sr = tid >> 1;
  const int sh = tid & 1;
  const float* xp = x + (size_t)(m0 + sr) * DD + sh * 32;
  const unsigned short* wp = WiT + (size_t)(n0 + sr) * DD + sh * 32;

  float bir[4];
#pragma unroll
  for (int j = 0; j < 4; ++j) bir[j] = bi[n0 + wn * 64 + j * 16 + (lane & 15)];

  f32x4 acc[4][4];
#pragma unroll
  for (int i = 0; i < 4; ++i)
#pragma unroll
    for (int j = 0; j < 4; ++j) acc[i][j] = (f32x4){0.f, 0.f, 0.f, 0.f};

  float4 xa[8];
  uint4 wa[4];
#pragma unroll
  for (int q = 0; q < 8; ++q) xa[q] = *reinterpret_cast<const float4*>(xp + q * 4);
#pragma unroll
  for (int c = 0; c < 4; ++c) wa[c] = *reinterpret_cast<const uint4*>(wp + c * 8);

  for (int kt = 0; kt < 8; ++kt) {
    __syncthreads();
    const int swz = (sr & 7) << 4;
#pragma unroll
    for (int c = 0; c < 4; ++c) {
      const float4 a = xa[2 * c], b = xa[2 * c + 1];
      uint4 u;
      u.x = (uint32_t)f2bf(a.x) | ((uint32_t)f2bf(a.y) << 16);
      u.y = (uint32_t)f2bf(a.z) | ((uint32_t)f2bf(a.w) << 16);
      u.z = (uint32_t)f2bf(b.x) | ((uint32_t)f2bf(b.y) << 16);
      u.w = (uint32_t)f2bf(b.z) | ((uint32_t)f2bf(b.w) << 16);
      const int off = sr * 128 + ((sh * 64 + c * 16) ^ swz);
      *reinterpret_cast<uint4*>(reinterpret_cast<char*>(Al) + off) = u;
    }
#pragma unroll
    for (int c = 0; c < 4; ++c) {
      const int off = sr * 128 + ((sh * 64 + c * 16) ^ swz);
      *reinterpret_cast<uint4*>(reinterpret_cast<char*>(Bl) + off) = wa[c];
    }
    if (kt < 7) {
#pragma unroll
      for (int q = 0; q < 8; ++q)
        xa[q] = *reinterpret_cast<const float4*>(xp + (kt + 1) * 64 + q * 4);
#pragma unroll
      for (int c = 0; c < 4; ++c)
        wa[c] = *reinterpret_cast<const uint4*>(wp + (kt + 1) * 64 + c * 8);
    }
    __syncthreads();
#pragma unroll
    for (int kk = 0; kk < 2; ++kk) {
      s16x8 af[4], bfr[4];
      const int kb = kk * 64 + ((lane >> 4) << 4);
      const int sw = (lane & 7) << 4;
#pragma unroll
      for (int i = 0; i < 4; ++i) {
        const int row = wm * 64 + i * 16 + (lane & 15);
        af[i] = ldsfrag(reinterpret_cast<const char*>(Al) + row * 128 + (kb ^ sw));
      }
#pragma unroll
      for (int j = 0; j < 4; ++j) {
        const int row = wn * 64 + j * 16 + (lane & 15);
        bfr[j] = ldsfrag(reinterpret_cast<const char*>(Bl) + row * 128 + (kb ^ sw));
      }
#pragma unroll
      for (int i = 0; i < 4; ++i)
#pragma unroll
        for (int j = 0; j < 4; ++j)
          acc[i][j] = __builtin_amdgcn_mfma_f32_16x16x32_bf16(af[i], bfr[j], acc[i][j], 0, 0, 0);
    }
  }
#pragma unroll
  for (int i = 0; i < 4; ++i) {
    const int gr0 = m0 + wm * 64 + i * 16 + ((lane >> 4) << 2);
#pragma unroll
    for (int j = 0; j < 4; ++j) {
      const int gc = n0 + wn * 64 + j * 16 + (lane & 15);
#pragma unroll
      for (int r = 0; r < 4; ++r)
        gi[(size_t)(gr0 + r) * 1536 + gc] = f2bf(acc[i][j][r] + bir[j]);
    }
  }
}

// ---------------- rnnB helpers ----------------
static __device__ __forceinline__ unsigned rmask16f(const int* resets, int rmode,
                                                    long long tg, int row0) {
  unsigned m = 0;
  if (rmode) {
    const unsigned char* rb = reinterpret_cast<const unsigned char*>(resets);
    uint4 u = *reinterpret_cast<const uint4*>(rb + (size_t)tg * 128 + row0);
    unsigned w0 = u.x, w1 = u.y, w2 = u.z, w3 = u.w;
#pragma unroll
    for (int b = 0; b < 4; ++b) {
      if ((w0 >> (8 * b)) & 0xFFu) m |= 1u << (0 + b);
      if ((w1 >> (8 * b)) & 0xFFu) m |= 1u << (4 + b);
      if ((w2 >> (8 * b)) & 0xFFu) m |= 1u << (8 + b);
      if ((w3 >> (8 * b)) & 0xFFu) m |= 1u << (12 + b);
    }
  } else {
    const uint4* p = reinterpret_cast<const uint4*>(resets + (size_t)tg * 128 + row0);
#pragma unroll
    for (int q = 0; q < 4; ++q) {
      uint4 u = p[q];
      if (u.x) m |= 1u << (q * 4 + 0);
      if (u.y) m |= 1u << (q * 4 + 1);
      if (u.z) m |= 1u << (q * 4 + 2);
      if (u.w) m |= 1u << (q * 4 + 3);
    }
  }
  return m;
}

#define RNN_SMEM (98304 + 16384 + 26112)

__global__ __launch_bounds__(512) void rnnB(const unsigned short* __restrict__ gi,
                                            const unsigned short* __restrict__ Wpk,
                                            const float* __restrict__ bhn,
                                            const int* __restrict__ resets,
                                            float* hx, unsigned int* flg,
                                            const int* __restrict__ rmodep,
                                            float* __restrict__ ys,
                                            int t0, int tc) {
  extern __shared__ char smem[];
  char* Hlb = smem + 98304;
  float* ax = reinterpret_cast<float*>(smem + 114688);

  const int tid = threadIdx.x;
  const int lane = tid & 63;
  const int wv = tid >> 6;
  const int w = wv & 1, ks = wv >> 1;
  const int cj = blockIdx.x >> 3, rg = blockIdx.x & 7;
  const int ec = tid & 31, eb = tid >> 5;          // elementwise: col-in-32, row-in-16
  const int bglob = rg * 16 + eb;
  const int colglob = cj * 32 + ec;
  const int rmode = *rmodep;

  // stage Wh slice: [96 cols][512 k] bf16, xor-swizzled rows of 1024B
  {
    const unsigned short* wsrc = Wpk + (size_t)cj * 96 * 512;
    for (int q = 0; q < 12; ++q) {
      const int chunk = q * 512 + tid;
      const int col = chunk >> 6;
      const int co = chunk & 63;
      uint4 vv = *reinterpret_cast<const uint4*>(wsrc + col * 512 + ((co ^ (col & 7)) << 3));
      *reinterpret_cast<uint4*>(smem + col * 1024 + co * 16) = vv;
    }
  }

  const float bhn_c = bhn[colglob];
  float h_old = hx[(size_t)bglob * 512 + colglob];   // h(t0), parity 0

  // column-owner copy of the group's h panel: thread owns column `tid`
  float v[16];
  {
    const float* s0 = hx + (size_t)rg * 8192 + tid;  // parity 0
#pragma unroll
    for (int i = 0; i < 16; ++i) v[i] = s0[i * 512];
  }
  unsigned mask = rmask16f(resets, rmode, t0, rg * 16);
  uint32_t gir, giz, gin;
  {
    const unsigned short* gp = gi + (size_t)bglob * 1536 + colglob;  // t=0
    gir = gp[0]; giz = gp[512]; gin = gp[1024];
  }
  __syncthreads();  // Wh staged

  for (int t = 0; t < tc; ++t) {
    const long long tg = t0 + t;
    // ---- stage Hl: thread owns column tid, rows 0..15; reset-masked ----
#pragma unroll
    for (int i = 0; i < 16; ++i) {
      float x = ((mask >> i) & 1u) ? 0.f : v[i];
      const int off = i * 1024 + (((((tid * 2) >> 4) ^ (i & 7)) << 4) | ((tid & 7) * 2));
      *reinterpret_cast<unsigned short*>(Hlb + off) = f2bf(x);
    }
    __syncthreads();  // B1: Hl ready
    // ---- MFMA: out[col][row] partials over K-quarter ks, col-half w ----
    f32x4 acc[3];
#pragma unroll
    for (int g = 0; g < 3; ++g) acc[g] = (f32x4){0.f, 0.f, 0.f, 0.f};
    {
      const int rowb = lane & 15;
      const int kplus = (lane >> 4) << 4;
      const char* hrow = Hlb + rowb * 1024;
      const int hsw = (rowb & 7) << 4;
#pragma unroll
      for (int g = 0; g < 3; ++g) {
        const int col = g * 32 + w * 16 + (lane & 15);
        const char* wrow = smem + col * 1024;
        const int wsw = (col & 7) << 4;
#pragma unroll
        for (int kk = 0; kk < 4; ++kk) {
          const int kb = (ks * 128 + kk * 32) * 2 + kplus;
          s16x8 a = ldsfrag(wrow + (kb ^ wsw));
          s16x8 b = ldsfrag(hrow + (kb ^ hsw));
          acc[g] = __builtin_amdgcn_mfma_f32_16x16x32_bf16(a, b, acc[g], 0, 0, 0);
        }
      }
    }
    {  // partials -> LDS (padded stride 17)
      const int mh = (lane >> 4) << 2, nn = lane & 15;
#pragma unroll
      for (int g = 0; g < 3; ++g) {
        float* dst = ax + ((ks * 2 + w) * 3 + g) * 272 + nn;
#pragma unroll
        for (int r = 0; r < 4; ++r) dst[(mh + r) * 17] = acc[g][r];
      }
    }
    __syncthreads();  // B2
    // ---- elementwise GRU update: one (row eb, col ec) per thread ----
    {
      const int wc = ec >> 4, mc = ec & 15;
      float s0a = 0.f, s1a = 0.f, s2a = 0.f;
#pragma unroll
      for (int k2 = 0; k2 < 4; ++k2) {
        const float* p = ax + ((k2 * 2 + wc) * 3) * 272 + mc * 17 + eb;
        s0a += p[0]; s1a += p[272]; s2a += p[544];
      }
      const float r = 1.f / (1.f + __expf(-(b2f(gir) + s0a)));
      const float z = 1.f / (1.f + __expf(-(b2f(giz) + s1a)));
      const float hu = ((mask >> eb) & 1u) ? 0.f : h_old;
      const float pre = b2f(gin) + r * (s2a + bhn_c);
      const float n = 1.f - 2.f / (1.f + __expf(2.f * pre));
      float hn = (1.f - z) * n + z * hu;
      hn = fminf(1.f, fmaxf(-1.f, hn));
      __builtin_nontemporal_store(hn, ys + ((size_t)tg * 128 + bglob) * 512 + colglob);
      float* hp = hx + (size_t)((tg + 1) & 1) * 65536 + (size_t)bglob * 512 + colglob;
      __hip_atomic_store(hp, hn, __ATOMIC_RELAXED, __HIP_MEMORY_SCOPE_AGENT);
      h_old = hn;
    }
    // ---- prefetch next step's gi + resets (hides under the poll wait) ----
    uint32_t ngr = 0, ngz = 0, ngn = 0;
    unsigned nmask = 0;
    const bool haveN = (t + 1 < tc);
    if (haveN) {
      const unsigned short* gp = gi + ((size_t)(t + 1) * 128 + bglob) * 1536 + colglob;
      ngr = gp[0]; ngz = gp[512]; ngn = gp[1024];
      nmask = rmask16f(resets, rmode, tg + 1, rg * 16);
    }
    __syncthreads();  // B3: drains every wave's h stores (vmcnt(0) before barrier)
    if (haveN) {
      const unsigned epoch = (unsigned)(tg + 1);
      if (tid == 0)
        __hip_atomic_store(flg + rg * 16 + cj, epoch,
                           __ATOMIC_RELAXED, __HIP_MEMORY_SCOPE_AGENT);
      if (wv == 0) {  // single polling wave; lanes 0-15 cover the 16 producers
        const unsigned int* fp = flg + rg * 16 + (lane & 15);
        for (int it = 0; it < (1 << 20); ++it) {   // watchdog: bounded spin
          bool ok = true;
          if (lane < 16)
            ok = (__hip_atomic_load(fp, __ATOMIC_RELAXED, __HIP_MEMORY_SCOPE_AGENT) >= epoch);
          if (__ballot(ok ? 1 : 0) == ~0ull) break;
          __builtin_amdgcn_s_sleep(1);
        }
      }
      __syncthreads();  // B4
      // ---- coalesced reload of the group's h(t+1) panel ----
      const float* src = hx + (size_t)((tg + 1) & 1) * 65536 + (size_t)rg * 8192 + tid;
#pragma unroll
      for (int i = 0; i < 16; ++i)
        v[i] = __hip_atomic_load(src + i * 512, __ATOMIC_RELAXED, __HIP_MEMORY_SCOPE_AGENT);
      gir = ngr; giz = ngz; gin = ngn; mask = nmask;
    }
  }
}

// ---------------- launch ----------------
extern "C" void kernel_launch(void* const* d_in, const int* in_sizes, int n_in,
                              void* d_out, int out_size, void* d_ws, size_t ws_size,
                              hipStream_t stream) {
  const float* h0 = (const float*)d_in[0];
  const float* ins = (const float*)d_in[1];
  const int* rst = (const int*)d_in[2];
  const float* Wi = (const float*)d_in[3];
  const float* bi = (const float*)d_in[4];
  const float* Whrz = (const float*)d_in[5];
  const float* Whn = (const float*)d_in[6];
  const float* bhn = (const float*)d_in[7];
  float* ys = (float*)d_out;

  char* ws = (char*)d_ws;
  unsigned short* WiT = (unsigned short*)(ws);              // 1,572,864 B
  unsigned short* Wpk = (unsigned short*)(ws + 1572864);    // 1,572,864 B
  float* hx = (float*)(ws + 3145728);                       //   524,288 B ([2][128][512])
  unsigned int* flg = (unsigned int*)(ws + 3670016);        //       512 B ([8][16])
  int* flag = (int*)(ws + 3670528);                         //         4 B (rmode)
  const size_t gi_off = 3674112;
  unsigned short* gi = (unsigned short*)(ws + gi_off);

  size_t avail = (ws_size > gi_off) ? (ws_size - gi_off) : 0;
  long long tcap = (long long)(avail / (128ull * 1536ull * 2ull));
  int Tc = (int)((tcap > 1024) ? 1024 : tcap);
  Tc &= ~1;
  if (Tc < 2) Tc = 2;

  hipMemsetAsync(ws + 3670016, 0, 1024, stream);  // flg + rmode
  hipMemcpyAsync(hx, h0, 262144, hipMemcpyDeviceToDevice, stream);  // h(0), parity 0
  prep<<<dim3(6144), dim3(256), 0, stream>>>(Wi, Whrz, Whn, WiT, Wpk);
  scanR<<<dim3(128), dim3(256), 0, stream>>>(rst, flag);
  hipFuncSetAttribute((const void*)rnnB, hipFuncAttributeMaxDynamicSharedMemorySize, RNN_SMEM);

  for (int t0 = 0; t0 < 1024; t0 += Tc) {
    int tc = 1024 - t0;
    if (tc > Tc) tc = Tc;
    gemmA<<<dim3(12, tc), dim3(256), 0, stream>>>(ins + (size_t)t0 * 65536, WiT, bi, gi);
    rnnB<<<dim3(128), dim3(512), RNN_SMEM, stream>>>(gi, Wpk, bhn, rst, hx, flg,
                                                     flag, ys, t0, tc);
  }
}